// Round 2
// baseline (200.600 us; speedup 1.0000x reference)
//
#include <hip/hip_runtime.h>
#include <math.h>

// DCCA loss: H1,H2 (m=2048, n=64, k=128) fp32.
// Gram stage: bf16 hi/lo split MFMA (32x32x16), 3 Grams, symmetric lower-only for S11/S22.
// Solve stage: Cholesky + triangular solves (unchanged from round 1, known-correct).
#define MBATCH 2048
#define TPB 4
#define GRID1 (MBATCH / TPB)   // 512 blocks
#define RSU 136                // LDS row stride in bf16 elems (272B, 16B-aligned)
#define PLANE (64 * RSU)       // 8704 elems per plane

// c = (1 - 1/m)^2 / (m*(m-1)) = 2047 / 2048^3
#define CSCALE 2.3830240e-7f
#define RIDGE 1e-4f

typedef __bf16 bf16x8 __attribute__((ext_vector_type(8)));
typedef float f32x16 __attribute__((ext_vector_type(16)));

#define MFMA32(A, B, C) __builtin_amdgcn_mfma_f32_32x32x16_bf16(A, B, C, 0, 0, 0)

__global__ __launch_bounds__(256, 2) void gram_kernel(const float* __restrict__ H1,
                                                      const float* __restrict__ H2,
                                                      float* __restrict__ sig) {
    // 4 planes (v1hi, v1lo, v2hi, v2lo) of [64][RSU] bf16 = 69632 B; reduction overlay 40960 B
    __shared__ float ldsraw[(4 * PLANE) / 2];
    __bf16* lds = (__bf16*)ldsraw;
    float* red = ldsraw;

    const int tid = threadIdx.x;
    const int w = tid >> 6;       // wave 0..3
    const int lane = tid & 63;
    const int l31 = lane & 31;
    const int lhi = lane >> 5;

    // 10 quadrant accumulators:
    // 0..2 : S11 (0,0),(1,0),(1,1)   3..5 : S22 same   6..9 : S12 (0,0),(0,1),(1,0),(1,1)
    f32x16 acc[10] = {};

    for (int t = 0; t < TPB; ++t) {
        const size_t base = (size_t)(blockIdx.x * TPB + t) * (64 * 128);
        __syncthreads();  // protect LDS vs previous iteration's fragment reads
        #pragma unroll
        for (int v = 0; v < 2; ++v) {
            const float* __restrict__ Hsrc = v ? H2 : H1;
            __bf16* plh = lds + (2 * v + 0) * PLANE;
            __bf16* pll = lds + (2 * v + 1) * PLANE;
            #pragma unroll
            for (int it = 0; it < 4; ++it) {
                int chunk = it * 256 + tid;       // 1024 chunks of 8 floats
                int r = chunk >> 4;               // row 0..63
                int c8 = chunk & 15;              // 8-col group
                const float* src = Hsrc + base + r * 128 + c8 * 8;
                float4 u0 = *(const float4*)(src);
                float4 u1 = *(const float4*)(src + 4);
                float f[8] = {u0.x, u0.y, u0.z, u0.w, u1.x, u1.y, u1.z, u1.w};
                bf16x8 hi, lo;
                #pragma unroll
                for (int j = 0; j < 8; ++j) {
                    __bf16 h = (__bf16)f[j];
                    hi[j] = h;
                    lo[j] = (__bf16)(f[j] - (float)h);  // residual exact in fp32
                }
                *(bf16x8*)&plh[r * RSU + c8 * 8] = hi;
                *(bf16x8*)&pll[r * RSU + c8 * 8] = lo;
            }
        }
        __syncthreads();

        #pragma unroll 1
        for (int ts = 0; ts < 2; ++ts) {
            const int kt = w + 4 * ts;            // this wave's k-step (of 8)
            const int kcol = kt * 16 + lhi * 8;
            bf16x8 f1h[2], f1l[2], f2h[2], f2l[2];
            #pragma unroll
            for (int blk = 0; blk < 2; ++blk) {
                const int row = blk * 32 + l31;
                f1h[blk] = *(const bf16x8*)&lds[0 * PLANE + row * RSU + kcol];
                f1l[blk] = *(const bf16x8*)&lds[1 * PLANE + row * RSU + kcol];
                f2h[blk] = *(const bf16x8*)&lds[2 * PLANE + row * RSU + kcol];
                f2l[blk] = *(const bf16x8*)&lds[3 * PLANE + row * RSU + kcol];
            }
            // S11 lower quadrants
            acc[0] = MFMA32(f1h[0], f1h[0], acc[0]);
            acc[0] = MFMA32(f1h[0], f1l[0], acc[0]);
            acc[0] = MFMA32(f1l[0], f1h[0], acc[0]);
            acc[1] = MFMA32(f1h[1], f1h[0], acc[1]);
            acc[1] = MFMA32(f1h[1], f1l[0], acc[1]);
            acc[1] = MFMA32(f1l[1], f1h[0], acc[1]);
            acc[2] = MFMA32(f1h[1], f1h[1], acc[2]);
            acc[2] = MFMA32(f1h[1], f1l[1], acc[2]);
            acc[2] = MFMA32(f1l[1], f1h[1], acc[2]);
            // S22 lower quadrants
            acc[3] = MFMA32(f2h[0], f2h[0], acc[3]);
            acc[3] = MFMA32(f2h[0], f2l[0], acc[3]);
            acc[3] = MFMA32(f2l[0], f2h[0], acc[3]);
            acc[4] = MFMA32(f2h[1], f2h[0], acc[4]);
            acc[4] = MFMA32(f2h[1], f2l[0], acc[4]);
            acc[4] = MFMA32(f2l[1], f2h[0], acc[4]);
            acc[5] = MFMA32(f2h[1], f2h[1], acc[5]);
            acc[5] = MFMA32(f2h[1], f2l[1], acc[5]);
            acc[5] = MFMA32(f2l[1], f2h[1], acc[5]);
            // S12 all quadrants (A=view1 block qi, B=view2 block qj)
            acc[6] = MFMA32(f1h[0], f2h[0], acc[6]);
            acc[6] = MFMA32(f1h[0], f2l[0], acc[6]);
            acc[6] = MFMA32(f1l[0], f2h[0], acc[6]);
            acc[7] = MFMA32(f1h[0], f2h[1], acc[7]);
            acc[7] = MFMA32(f1h[0], f2l[1], acc[7]);
            acc[7] = MFMA32(f1l[0], f2h[1], acc[7]);
            acc[8] = MFMA32(f1h[1], f2h[0], acc[8]);
            acc[8] = MFMA32(f1h[1], f2l[0], acc[8]);
            acc[8] = MFMA32(f1l[1], f2h[0], acc[8]);
            acc[9] = MFMA32(f1h[1], f2h[1], acc[9]);
            acc[9] = MFMA32(f1h[1], f2l[1], acc[9]);
            acc[9] = MFMA32(f1l[1], f2h[1], acc[9]);
        }
    }

    // Cross-wave reduction in LDS, then one global atomic set per block.
    __syncthreads();
    for (int i = tid; i < 10240; i += 256) red[i] = 0.0f;
    __syncthreads();
    #pragma unroll
    for (int q = 0; q < 10; ++q) {
        #pragma unroll
        for (int rg = 0; rg < 16; ++rg) {
            // C/D layout (32x32): col = lane&31, row = (rg&3) + 8*(rg>>2) + 4*(lane>>5)
            int row = (rg & 3) + 8 * (rg >> 2) + 4 * lhi;
            atomicAdd(&red[q * 1024 + row * 32 + l31], acc[q][rg]);
        }
    }
    __syncthreads();
    #pragma unroll
    for (int q = 0; q < 10; ++q) {
        const int mat = (q < 3) ? 0 : ((q < 6) ? 1 : 2);
        const int qi = (q < 6) ? ((q == 0 || q == 3) ? 0 : 1) : ((q <= 7) ? 0 : 1);
        const int qj = (q < 6) ? ((q == 2 || q == 5) ? 1 : 0) : ((q == 7 || q == 9) ? 1 : 0);
        for (int jx = tid; jx < 1024; jx += 256) {
            int r = jx >> 5, c = jx & 31;
            atomicAdd(&sig[mat * 4096 + (qi * 32 + r) * 64 + qj * 32 + c],
                      red[q * 1024 + jx]);
        }
    }
}

// One block. Scale+ridge, two Choleskys (one wave each), two unrolled triangular
// solves, Frobenius norm, -sqrt. (Unchanged from round 1 — known correct.)
__global__ __launch_bounds__(256) void solve_kernel(const float* __restrict__ sig,
                                                    float* __restrict__ out) {
    __shared__ float A1[64 * 68];
    __shared__ float A2[64 * 68];
    __shared__ float S [64 * 68];
    __shared__ float AS[64 * 68];
    __shared__ float Ldi[2][64];
    const int tid = threadIdx.x;

    for (int idx = tid; idx < 4096; idx += 256) {
        int r = idx >> 6, q = idx & 63;
        float rg = (r == q) ? RIDGE : 0.0f;
        A1[r * 68 + q] = CSCALE * sig[idx] + rg;
        A2[r * 68 + q] = CSCALE * sig[4096 + idx] + rg;
        S [r * 68 + q] = CSCALE * sig[8192 + idx];
    }
    __syncthreads();

    if (tid < 128) {
        float* A = (tid >= 64) ? A2 : A1;
        const int half = tid >> 6;
        const int lane = tid & 63;
        float Lrow[64];
        #pragma unroll
        for (int j = 0; j < 64; ++j) {
            float s = A[lane * 68 + j];
            #pragma unroll
            for (int tt = 0; tt < j; ++tt)
                s -= Lrow[tt] * A[j * 68 + tt];
            float dj = __shfl(s, j, 64);
            float Ljj = sqrtf(dj);
            float v = s / Ljj;
            Lrow[j] = v;
            if (lane >= j) A[lane * 68 + j] = v;
            if (lane == j) Ldi[half][j] = 1.0f / Ljj;
        }
    }
    __syncthreads();

    if (tid < 64) {
        const int c = tid;
        float y[64];
        #pragma unroll
        for (int r = 0; r < 64; ++r) {
            float s = S[r * 68 + c];
            #pragma unroll
            for (int tt = 0; tt < r; ++tt) s -= A1[r * 68 + tt] * y[tt];
            y[r] = s * Ldi[0][r];
            AS[r * 68 + c] = y[r];
        }
    }
    __syncthreads();

    if (tid < 64) {
        const int c = tid;
        float z[64];
        float nrm = 0.0f;
        #pragma unroll
        for (int r = 0; r < 64; ++r) {
            float s = AS[c * 68 + r];
            #pragma unroll
            for (int tt = 0; tt < r; ++tt) s -= A2[r * 68 + tt] * z[tt];
            z[r] = s * Ldi[1][r];
            nrm += z[r] * z[r];
        }
        #pragma unroll
        for (int off = 32; off; off >>= 1) nrm += __shfl_xor(nrm, off, 64);
        if (tid == 0) out[0] = -sqrtf(nrm);
    }
}

extern "C" void kernel_launch(void* const* d_in, const int* in_sizes, int n_in,
                              void* d_out, int out_size, void* d_ws, size_t ws_size,
                              hipStream_t stream) {
    const float* H1 = (const float*)d_in[0];
    const float* H2 = (const float*)d_in[1];
    float* sig = (float*)d_ws;  // 3 * 4096 floats = 48 KB accumulators

    hipMemsetAsync(d_ws, 0, 3 * 4096 * sizeof(float), stream);
    gram_kernel<<<GRID1, 256, 0, stream>>>(H1, H2, sig);
    solve_kernel<<<1, 256, 0, stream>>>(sig, (float*)d_out);
}